// Round 2
// baseline (292.157 us; speedup 1.0000x reference)
//
#include <hip/hip_runtime.h>
#include <hip/hip_bf16.h>

#define GRID_R   256
#define GRID_RR  65536       // 256*256
#define NVOX     16777216    // 256^3
#define NBRK     128         // bricks per axis
#define INV_2VS  31.875f     // 255/8 exact
#define INV_VS   63.75f      // 255/4 exact
#define VSF      0.015686275f // float(4/255)

__device__ __forceinline__ float h2f(unsigned short u) {
    union { unsigned short s; _Float16 f; } cv; cv.s = u; return (float)cv.f;
}
__device__ __forceinline__ unsigned f2h2(float a, float b) {  // pack two halves
    union { unsigned short s; _Float16 f; } ca, cb;
    ca.f = (_Float16)a; cb.f = (_Float16)b;
    return (unsigned)ca.s | ((unsigned)cb.s << 16);
}

// Reference boundary normals:
//   c==0:   (g1 - 1.5*g0 + 0.5*g2) * INV_2VS
//   c==255: (1.5*g255 - 0.5*g253 - g254) * INV_2VS
//   else:   (g[c+1] - g[c-1]) * INV_2VS

// ---------------- pre-pass: barrier-free column sweep ------------------------
// One thread = one (x,y) column over a 32-z segment. z-stencil from a sliding
// register window (prevlast | cur4 | nxt4.x). x/y neighbor columns read
// directly from global (L1/L2-hit: each line consumed ~8x by co-resident
// threads; 64 MB grid is L3-resident). No LDS, no __syncthreads.
//
// packed brick layout (consumed by gather): brick B=(bx*128+by)*128+bz,
// 64 B/brick = 8 uint2 slots, slot s = 4dx+2dy+dz. A lane with (dx,dy)
// writes slots {s,s+1} (dz=0,1) as one uint4 at byte offset 16*(2dx+dy);
// lanes t..t+3 of a quad cover one full 64 B line.
__global__ __launch_bounds__(256) void precompute_col_kernel(
    const float* __restrict__ grid,
    uint2*       __restrict__ packed)
{
    const int t   = threadIdx.x;
    const int bid = blockIdx.x;          // 2048 = 256 xy-patches * 8 z-segments
    const int zseg  = bid & 7;
    const int patch = bid >> 3;
    const int Xb = (patch >> 4) << 4;    // 16x16 columns per patch
    const int Yb = (patch & 15) << 4;

    const int dx = (t >> 1) & 1;
    const int dy = t & 1;
    const int bq = t >> 2;               // 0..63 : brick-in-patch
    const int pbx = bq >> 3, pby = bq & 7;
    const int x = Xb + (pbx << 1) + dx;
    const int y = Yb + (pby << 1) + dy;

    const bool xlo = (x == 0), xhi = (x == 255);
    const bool ylo = (y == 0), yhi = (y == 255);
    const bool xbd = xlo || xhi, ybd = ylo || yhi;

    const float* colC  = grid + (x << 16) + (y << 8);
    const float* colXm = grid + (max(x - 1, 0)   << 16) + (y << 8);
    const float* colXp = grid + (min(x + 1, 255) << 16) + (y << 8);
    const float* colYm = grid + (x << 16) + (max(y - 1, 0)   << 8);
    const float* colYp = grid + (x << 16) + (min(y + 1, 255) << 8);
    const float* colX2 = grid + ((xlo ? 2 : 253) << 16) + (y << 8);  // only read at x boundary
    const float* colY2 = grid + (x << 16) + ((ylo ? 2 : 253) << 8);  // only read at y boundary

    const int j0 = zseg << 3;            // float4 index base: 8 steps of 4 z
    float4 cur = *reinterpret_cast<const float4*>(colC + (j0 << 2));
    float prevlast = (j0 > 0) ? colC[(j0 << 2) - 1] : 0.0f;  // unused when z==0 (boundary formula)

    const int gbx = x >> 1, gby = y >> 1;
    uint4* outp = reinterpret_cast<uint4*>(packed)
                + ((((gbx << 7) + gby) << 7) + (j0 << 1)) * 4 + ((dx << 1) + dy);

    #pragma unroll
    for (int jj = 0; jj < 8; ++jj) {
        const int j  = j0 + jj;
        const int jn = (j < 63) ? j + 1 : 63;   // clamp; value unused at z=255 (boundary formula)
        const float4 nxt = *reinterpret_cast<const float4*>(colC  + (jn << 2));
        const float4 vxm = *reinterpret_cast<const float4*>(colXm + (j  << 2));
        const float4 vxp = *reinterpret_cast<const float4*>(colXp + (j  << 2));
        const float4 vym = *reinterpret_cast<const float4*>(colYm + (j  << 2));
        const float4 vyp = *reinterpret_cast<const float4*>(colYp + (j  << 2));
        float4 vx2 = make_float4(0.f, 0.f, 0.f, 0.f);
        float4 vy2 = make_float4(0.f, 0.f, 0.f, 0.f);
        if (xbd) vx2 = *reinterpret_cast<const float4*>(colX2 + (j << 2));
        if (ybd) vy2 = *reinterpret_cast<const float4*>(colY2 + (j << 2));

        // register windows, all indices compile-time under full unroll
        const float cw[6]  = {prevlast, cur.x, cur.y, cur.z, cur.w, nxt.x};
        const float axm[4] = {vxm.x, vxm.y, vxm.z, vxm.w};
        const float axp[4] = {vxp.x, vxp.y, vxp.z, vxp.w};
        const float aym[4] = {vym.x, vym.y, vym.z, vym.w};
        const float ayp[4] = {vyp.x, vyp.y, vyp.z, vyp.w};
        const float ax2[4] = {vx2.x, vx2.y, vx2.z, vx2.w};
        const float ay2[4] = {vy2.x, vy2.y, vy2.z, vy2.w};

        unsigned h[8];
        #pragma unroll
        for (int q = 0; q < 4; ++q) {
            const int z = (j << 2) + q;
            const float g0 = cw[q + 1];

            float nx;
            if (xlo)      nx = (axp[q] - 1.5f*g0 + 0.5f*ax2[q]) * INV_2VS;
            else if (xhi) nx = (1.5f*g0 - 0.5f*ax2[q] - axm[q]) * INV_2VS;
            else          nx = (axp[q] - axm[q]) * INV_2VS;

            float ny;
            if (ylo)      ny = (ayp[q] - 1.5f*g0 + 0.5f*ay2[q]) * INV_2VS;
            else if (yhi) ny = (1.5f*g0 - 0.5f*ay2[q] - aym[q]) * INV_2VS;
            else          ny = (ayp[q] - aym[q]) * INV_2VS;

            float nz;
            if (z == 0)        nz = (cw[2] - 1.5f*cw[1] + 0.5f*cw[3]) * INV_2VS;
            else if (z == 255) nz = (1.5f*cw[4] - 0.5f*cw[2] - cw[3]) * INV_2VS;
            else               nz = (cw[q + 2] - cw[q]) * INV_2VS;

            h[2*q]     = f2h2(nx, ny);
            h[2*q + 1] = f2h2(nz, g0);
        }

        uint4 s0; s0.x = h[0]; s0.y = h[1]; s0.z = h[2]; s0.w = h[3];
        uint4 s1; s1.x = h[4]; s1.y = h[5]; s1.z = h[6]; s1.w = h[7];
        outp[(jj << 3)]     = s0;   // brick bz = 2j   (z = 4j, 4j+1)
        outp[(jj << 3) + 4] = s1;   // brick bz = 2j+1 (z = 4j+2, 4j+3)

        prevlast = cur.w;
        cur = nxt;
    }
}

// ---------------- gather pass: one thread per ray ----------------------------
// voxel_min_point is exactly -2 + vidx*VS in fp32, recomputed from vidx.
__global__ __launch_bounds__(256) void gather_kernel(
    const uint2* __restrict__ packed,
    const int*   __restrict__ vidx,
    const float* __restrict__ ipos,
    const int*   __restrict__ mask,
    float*       __restrict__ out,
    int n)
{
    int i = blockIdx.x * blockDim.x + threadIdx.x;
    if (i >= n) return;

    int x = vidx[3*i+0];
    int y = vidx[3*i+1];
    int z = vidx[3*i+2];

    float tx = (ipos[3*i+0] - (-2.0f + (float)x * VSF)) * INV_VS;
    float ty = (ipos[3*i+1] - (-2.0f + (float)y * VSF)) * INV_VS;
    float tz = (ipos[3*i+2] - (-2.0f + (float)z * VSF)) * INV_VS;

    int   m   = mask[i];
    float inv = 1.0f - (float)m;

    float ox = 1.0f - tx, oy = 1.0f - ty, oz = 1.0f - tz;
    // corner order k = dx*4 + dy*2 + dz — matches reference
    float w[8];
    w[0] = oz*oy*ox;  w[1] = tz*oy*ox;  w[2] = oz*ty*ox;  w[3] = tz*ty*ox;
    w[4] = oz*oy*tx;  w[5] = tz*oy*tx;  w[6] = oz*ty*tx;  w[7] = tz*ty*tx;

    float accx = 0.f, accy = 0.f, accz = 0.f;
    float gbase = 0.f;

    #pragma unroll
    for (int k = 0; k < 8; ++k) {
        int cx = x + (k >> 2), cy = y + ((k >> 1) & 1), cz = z + (k & 1);
        int B  = ((cx >> 1)*NBRK + (cy >> 1))*NBRK + (cz >> 1);
        int s  = (cx & 1)*4 + (cy & 1)*2 + (cz & 1);
        uint2 p = packed[B*8 + s];
        accx += h2f(p.x & 0xffff) * w[k];
        accy += h2f(p.x >> 16)    * w[k];
        accz += h2f(p.y & 0xffff) * w[k];
        if (k == 0) gbase = h2f(p.y >> 16);
    }

    float4 o;
    o.x = accx + inv;   // +(1-m) on all 8 corners distributes out (sum w = 1)
    o.y = accy + inv;
    o.z = accz + inv;
    o.w = fmaxf(-gbase, 0.0f) * (float)m;
    *reinterpret_cast<float4*>(out + 4*i) = o;
}

// ---------------- fallback: direct on-the-fly kernel -------------------------
__global__ __launch_bounds__(256) void sdf_grid_kernel(
    const float* __restrict__ grid,
    const int*   __restrict__ vidx,
    const float* __restrict__ ipos,
    const float* __restrict__ vmin,
    const int*   __restrict__ mask,
    float*       __restrict__ out,
    int n)
{
    int i = blockIdx.x * blockDim.x + threadIdx.x;
    if (i >= n) return;
    int x = vidx[3*i+0], y = vidx[3*i+1], z = vidx[3*i+2];
    float tx = (ipos[3*i+0] - vmin[3*i+0]) * INV_VS;
    float ty = (ipos[3*i+1] - vmin[3*i+1]) * INV_VS;
    float tz = (ipos[3*i+2] - vmin[3*i+2]) * INV_VS;
    int   m   = mask[i];
    float inv = 1.0f - (float)m;
    float ox = 1.0f - tx, oy = 1.0f - ty, oz = 1.0f - tz;
    float w[8];
    w[0] = oz*oy*ox;  w[1] = tz*oy*ox;  w[2] = oz*ty*ox;  w[3] = tz*ty*ox;
    w[4] = oz*oy*tx;  w[5] = tz*oy*tx;  w[6] = oz*ty*tx;  w[7] = tz*ty*tx;
    int base = z + GRID_R*y + GRID_RR*x;
    float nout[3];
    #pragma unroll
    for (int a = 0; a < 3; ++a) {
        const int s  = (a==0) ? GRID_RR : (a==1) ? GRID_R : 1;
        const int c0 = (a==0) ? x : (a==1) ? y : z;
        float acc = 0.0f;
        #pragma unroll
        for (int k = 0; k < 8; ++k) {
            const int dx = k>>2, dy = (k>>1)&1, dz = k&1;
            const int b  = base + dz + GRID_R*dy + GRID_RR*dx;
            const int cc = c0 + ((a==0) ? dx : (a==1) ? dy : dz);
            float v;
            if (cc == 0)            v = grid[b+s] - (3.0f*grid[b] - grid[b+2*s])*0.5f;
            else if (cc == GRID_R-1) v = (3.0f*grid[b] - grid[b-2*s])*0.5f - grid[b-s];
            else                    v = grid[b+s] - grid[b-s];
            acc += (v*INV_2VS + inv) * w[k];
        }
        nout[a] = acc;
    }
    float gx = fmaxf(-grid[base], 0.0f) * (float)m;
    float4 o; o.x = nout[0]; o.y = nout[1]; o.z = nout[2]; o.w = gx;
    *reinterpret_cast<float4*>(out + 4*i) = o;
}

extern "C" void kernel_launch(void* const* d_in, const int* in_sizes, int n_in,
                              void* d_out, int out_size, void* d_ws, size_t ws_size,
                              hipStream_t stream) {
    const float* grid = (const float*)d_in[0];
    const int*   vidx = (const int*)d_in[1];
    const float* ipos = (const float*)d_in[2];
    const float* vmin = (const float*)d_in[3];
    const int*   mask = (const int*)d_in[4];
    float*       out  = (float*)d_out;

    const int n = in_sizes[4];          // H*W rays
    const int block = 256;

    if (ws_size >= (size_t)NVOX * 8) {
        uint2* packed = (uint2*)d_ws;
        // 256 xy-patches (16x16 columns) x 8 z-segments (32 z each)
        precompute_col_kernel<<<2048, block, 0, stream>>>(grid, packed);
        gather_kernel<<<(n + block - 1) / block, block, 0, stream>>>(
            packed, vidx, ipos, mask, out, n);
    } else {
        sdf_grid_kernel<<<(n + block - 1) / block, block, 0, stream>>>(
            grid, vidx, ipos, vmin, mask, out, n);
    }
}

// Round 4
// 236.197 us; speedup vs baseline: 1.2369x; 1.2369x over previous
//
#include <hip/hip_runtime.h>
#include <hip/hip_bf16.h>

#define GRID_R   256
#define GRID_RR  65536       // 256*256
#define NVOX     16777216    // 256^3
#define NBRK     128         // bricks per axis
#define INV_2VS  31.875f     // 255/8 exact
#define INV_VS   63.75f      // 255/4 exact
#define VSF      0.015686275f // float(4/255)

__device__ __forceinline__ float h2f(unsigned short u) {
    union { unsigned short s; _Float16 f; } cv; cv.s = u; return (float)cv.f;
}
__device__ __forceinline__ unsigned f2h2(float a, float b) {  // pack two halves
    union { unsigned short s; _Float16 f; } ca, cb;
    ca.f = (_Float16)a; cb.f = (_Float16)b;
    return (unsigned)ca.s | ((unsigned)cb.s << 16);
}

// Reference boundary normals:
//   c==0:   (g1 - 1.5*g0 + 0.5*g2) * INV_2VS
//   c==255: (1.5*g255 - 0.5*g253 - g254) * INV_2VS
//   else:   (g[c+1] - g[c-1]) * INV_2VS

// ---------------- pre-pass: LDS-tiled stencil (verified, ~61 us) -------------
// Tile = 8x8x32 voxels = 4x4x16 bricks, 1 brick/thread (256 threads).
// Phase 1: coalesced float4 loads of the 10x10x40 halo window into LDS.
// Phase 2: per-brick normals from LDS.
// Phase 3: stage packed bricks in the SAME LDS (aliased with halo buffer,
//          dead by then), write 256B-contiguous dwordx4 stores.
// packed brick layout: 64 B/brick = 8 uint2 slots, slot s = dx*4+dy*2+dz,
// brick B = (bx*128 + by)*128 + bz.
__global__ __launch_bounds__(256, 6) void precompute_tile_kernel(
    const float* __restrict__ grid,
    uint2*       __restrict__ packed)
{
    __shared__ uint4 sm[1024];                    // 16384 B, dual-purpose
    float* ls = reinterpret_cast<float*>(sm);     // phase 1/2: 10*10*40 floats = 16000 B

    const int bid = blockIdx.x;         // 8192 = 32 x 32 x 8 tiles
    const int t   = threadIdx.x;
    const int tz  = bid & 7;
    const int ty  = (bid >> 3) & 31;
    const int tx  = bid >> 8;
    const int xt0 = tx << 3, yt0 = ty << 3, zt0 = tz << 5;

    // ---- phase 1: load 10x10 rows x 40 z-floats (aligned float4) ----
    #pragma unroll
    for (int it = 0; it < 4; ++it) {
        int w = t + (it << 8);
        if (w < 1000) {
            int lx  = w / 100;
            int rem = w - lx * 100;
            int ly  = rem / 10;
            int seg = rem - ly * 10;
            int gx = min(max(xt0 - 1 + lx, 0), 255);
            int gy = min(max(yt0 - 1 + ly, 0), 255);
            int zb = min(max(zt0 - 4 + (seg << 2), 0), 252);
            // clamped (out-of-range) slots are never consumed by the formulas
            float4 v = *reinterpret_cast<const float4*>(
                grid + (gx << 16) + (gy << 8) + zb);
            *reinterpret_cast<float4*>(&ls[(lx * 10 + ly) * 40 + (seg << 2)]) = v;
        }
    }
    __syncthreads();

    // ---- phase 2: one 2x2x2 brick per thread from LDS ----
    const int lbz = t & 15, lby = (t >> 4) & 3, lbx = t >> 6;
    const int Lx = lbx << 1, Ly = lby << 1, Lz = lbz << 1;
    #define S(ix,iy,iz) ls[((1 + Lx + (ix)) * 10 + (1 + Ly + (iy))) * 40 + (4 + Lz + (iz))]

    float c[2][2][2], xlo[2][2], xhi[2][2], ylo[2][2], yhi[2][2], zlo[2][2], zhi[2][2];
    #pragma unroll
    for (int dy = 0; dy < 2; ++dy)
    #pragma unroll
    for (int dz = 0; dz < 2; ++dz) { xlo[dy][dz] = S(-1, dy, dz); xhi[dy][dz] = S(2, dy, dz); }
    #pragma unroll
    for (int dx = 0; dx < 2; ++dx)
    #pragma unroll
    for (int dz = 0; dz < 2; ++dz) { ylo[dx][dz] = S(dx, -1, dz); yhi[dx][dz] = S(dx, 2, dz); }
    #pragma unroll
    for (int dx = 0; dx < 2; ++dx)
    #pragma unroll
    for (int dy = 0; dy < 2; ++dy) { zlo[dx][dy] = S(dx, dy, -1); zhi[dx][dy] = S(dx, dy, 2); }
    #pragma unroll
    for (int dx = 0; dx < 2; ++dx)
    #pragma unroll
    for (int dy = 0; dy < 2; ++dy)
    #pragma unroll
    for (int dz = 0; dz < 2; ++dz) c[dx][dy][dz] = S(dx, dy, dz);
    #undef S

    const int x0 = xt0 + Lx, y0 = yt0 + Ly, z0 = zt0 + Lz;
    const bool xb0 = (x0 == 0), xb1 = (x0 + 1 == 255);
    const bool yb0 = (y0 == 0), yb1 = (y0 + 1 == 255);
    const bool zb0 = (z0 == 0), zb1 = (z0 + 1 == 255);

    uint2 slot[8];
    #pragma unroll
    for (int dx = 0; dx < 2; ++dx)
    #pragma unroll
    for (int dy = 0; dy < 2; ++dy)
    #pragma unroll
    for (int dz = 0; dz < 2; ++dz) {
        float g0 = c[dx][dy][dz];

        float nx;
        if (xb0 && dx == 0)      nx = (c[1][dy][dz] - 1.5f*g0 + 0.5f*xhi[dy][dz]) * INV_2VS;
        else if (xb1 && dx == 1) nx = (1.5f*g0 - 0.5f*xlo[dy][dz] - c[0][dy][dz]) * INV_2VS;
        else nx = ((dx ? xhi[dy][dz] : c[1][dy][dz]) - (dx ? c[0][dy][dz] : xlo[dy][dz])) * INV_2VS;

        float ny;
        if (yb0 && dy == 0)      ny = (c[dx][1][dz] - 1.5f*g0 + 0.5f*yhi[dx][dz]) * INV_2VS;
        else if (yb1 && dy == 1) ny = (1.5f*g0 - 0.5f*ylo[dx][dz] - c[dx][0][dz]) * INV_2VS;
        else ny = ((dy ? yhi[dx][dz] : c[dx][1][dz]) - (dy ? c[dx][0][dz] : ylo[dx][dz])) * INV_2VS;

        float nz;
        if (zb0 && dz == 0)      nz = (c[dx][dy][1] - 1.5f*g0 + 0.5f*zhi[dx][dy]) * INV_2VS;
        else if (zb1 && dz == 1) nz = (1.5f*g0 - 0.5f*zlo[dx][dy] - c[dx][dy][0]) * INV_2VS;
        else nz = ((dz ? zhi[dx][dy] : c[dx][dy][1]) - (dz ? c[dx][dy][0] : zlo[dx][dy])) * INV_2VS;

        int s = dx*4 + dy*2 + dz;
        slot[s].x = f2h2(nx, ny);
        slot[s].y = f2h2(nz, g0);
    }

    // ---- phase 3: stage in aliased LDS (brick-linear == global order) -------
    __syncthreads();   // all phase-2 LDS reads done before overwriting ls
    #pragma unroll
    for (int j = 0; j < 4; ++j) {
        uint4 st; st.x = slot[2*j].x;   st.y = slot[2*j].y;
                  st.z = slot[2*j+1].x; st.w = slot[2*j+1].y;
        sm[t*4 + j] = st;
    }
    __syncthreads();

    const int chunk = t >> 4;           // (lbx,lby) group: 16 bricks along bz
    const int idx   = t & 15;
    const int cbx = (tx << 2) + (chunk >> 2);
    const int cby = (ty << 2) + (chunk & 3);
    const long long Bg = ((long long)(cbx * NBRK + cby)) * NBRK + (tz << 4);
    uint4*       gdst = reinterpret_cast<uint4*>(packed) + Bg * 4;
    const uint4* lsrc = &sm[chunk << 6];
    #pragma unroll
    for (int j = 0; j < 4; ++j)
        gdst[idx + (j << 4)] = lsrc[idx + (j << 4)];
}

// ---------------- gather pass: one thread per ray ----------------------------
// Two-phase: all 8 corner loads issued into named registers (all in flight)
// BEFORE ipos/mask/weights are touched. Targets the latency limit seen at
// VGPR_Count=20 (compiler was draining loads in batches of 2-3).
__global__ __launch_bounds__(256) void gather_kernel(
    const uint2* __restrict__ packed,
    const int*   __restrict__ vidx,
    const float* __restrict__ ipos,
    const int*   __restrict__ mask,
    float*       __restrict__ out,
    int n)
{
    int i = blockIdx.x * blockDim.x + threadIdx.x;
    if (i >= n) return;

    const int x = vidx[3*i+0];
    const int y = vidx[3*i+1];
    const int z = vidx[3*i+2];

    // ---- phase A: compute all 8 slot offsets, issue all 8 loads ----
    int off[8];
    #pragma unroll
    for (int k = 0; k < 8; ++k) {
        int cx = x + (k >> 2), cy = y + ((k >> 1) & 1), cz = z + (k & 1);
        int B  = ((cx >> 1)*NBRK + (cy >> 1))*NBRK + (cz >> 1);
        int s  = (cx & 1)*4 + (cy & 1)*2 + (cz & 1);
        off[k] = B*8 + s;
    }
    const uint2 p0 = packed[off[0]];
    const uint2 p1 = packed[off[1]];
    const uint2 p2 = packed[off[2]];
    const uint2 p3 = packed[off[3]];
    const uint2 p4 = packed[off[4]];
    const uint2 p5 = packed[off[5]];
    const uint2 p6 = packed[off[6]];
    const uint2 p7 = packed[off[7]];

    // ---- phase B: inputs + weights (overlaps with corner-load latency) ----
    float tx = (ipos[3*i+0] - (-2.0f + (float)x * VSF)) * INV_VS;
    float ty = (ipos[3*i+1] - (-2.0f + (float)y * VSF)) * INV_VS;
    float tz = (ipos[3*i+2] - (-2.0f + (float)z * VSF)) * INV_VS;

    const int   m   = mask[i];
    const float inv = 1.0f - (float)m;

    float ox = 1.0f - tx, oy = 1.0f - ty, oz = 1.0f - tz;
    // corner order k = dx*4 + dy*2 + dz — matches reference
    float w[8];
    w[0] = oz*oy*ox;  w[1] = tz*oy*ox;  w[2] = oz*ty*ox;  w[3] = tz*ty*ox;
    w[4] = oz*oy*tx;  w[5] = tz*oy*tx;  w[6] = oz*ty*tx;  w[7] = tz*ty*tx;

    // ---- phase C: accumulate ----
    uint2 p[8] = {p0, p1, p2, p3, p4, p5, p6, p7};
    float accx = 0.f, accy = 0.f, accz = 0.f;
    #pragma unroll
    for (int k = 0; k < 8; ++k) {
        accx += h2f(p[k].x & 0xffff) * w[k];
        accy += h2f(p[k].x >> 16)    * w[k];
        accz += h2f(p[k].y & 0xffff) * w[k];
    }
    const float gbase = h2f(p0.y >> 16);

    float4 o;
    o.x = accx + inv;   // +(1-m) on all 8 corners distributes out (sum w = 1)
    o.y = accy + inv;
    o.z = accz + inv;
    o.w = fmaxf(-gbase, 0.0f) * (float)m;
    *reinterpret_cast<float4*>(out + 4*i) = o;
}

// ---------------- fallback: direct on-the-fly kernel -------------------------
__global__ __launch_bounds__(256) void sdf_grid_kernel(
    const float* __restrict__ grid,
    const int*   __restrict__ vidx,
    const float* __restrict__ ipos,
    const float* __restrict__ vmin,
    const int*   __restrict__ mask,
    float*       __restrict__ out,
    int n)
{
    int i = blockIdx.x * blockDim.x + threadIdx.x;
    if (i >= n) return;
    int x = vidx[3*i+0], y = vidx[3*i+1], z = vidx[3*i+2];
    float tx = (ipos[3*i+0] - vmin[3*i+0]) * INV_VS;
    float ty = (ipos[3*i+1] - vmin[3*i+1]) * INV_VS;
    float tz = (ipos[3*i+2] - vmin[3*i+2]) * INV_VS;
    int   m   = mask[i];
    float inv = 1.0f - (float)m;
    float ox = 1.0f - tx, oy = 1.0f - ty, oz = 1.0f - tz;
    float w[8];
    w[0] = oz*oy*ox;  w[1] = tz*oy*ox;  w[2] = oz*ty*ox;  w[3] = tz*ty*ox;
    w[4] = oz*oy*tx;  w[5] = tz*oy*tx;  w[6] = oz*ty*tx;  w[7] = tz*ty*tx;
    int base = z + GRID_R*y + GRID_RR*x;
    float nout[3];
    #pragma unroll
    for (int a = 0; a < 3; ++a) {
        const int s  = (a==0) ? GRID_RR : (a==1) ? GRID_R : 1;
        const int c0 = (a==0) ? x : (a==1) ? y : z;
        float acc = 0.0f;
        #pragma unroll
        for (int k = 0; k < 8; ++k) {
            const int dx = k>>2, dy = (k>>1)&1, dz = k&1;
            const int b  = base + dz + GRID_R*dy + GRID_RR*dx;
            const int cc = c0 + ((a==0) ? dx : (a==1) ? dy : dz);
            float v;
            if (cc == 0)            v = grid[b+s] - (3.0f*grid[b] - grid[b+2*s])*0.5f;
            else if (cc == GRID_R-1) v = (3.0f*grid[b] - grid[b-2*s])*0.5f - grid[b-s];
            else                    v = grid[b+s] - grid[b-s];
            acc += (v*INV_2VS + inv) * w[k];
        }
        nout[a] = acc;
    }
    float gx = fmaxf(-grid[base], 0.0f) * (float)m;
    float4 o; o.x = nout[0]; o.y = nout[1]; o.z = nout[2]; o.w = gx;
    *reinterpret_cast<float4*>(out + 4*i) = o;
}

extern "C" void kernel_launch(void* const* d_in, const int* in_sizes, int n_in,
                              void* d_out, int out_size, void* d_ws, size_t ws_size,
                              hipStream_t stream) {
    const float* grid = (const float*)d_in[0];
    const int*   vidx = (const int*)d_in[1];
    const float* ipos = (const float*)d_in[2];
    const float* vmin = (const float*)d_in[3];
    const int*   mask = (const int*)d_in[4];
    float*       out  = (float*)d_out;

    const int n = in_sizes[4];          // H*W rays
    const int block = 256;

    if (ws_size >= (size_t)NVOX * 8) {
        uint2* packed = (uint2*)d_ws;
        // 32 x 32 x 8 tiles of 8x8x32 voxels = 8192 blocks
        precompute_tile_kernel<<<8192, block, 0, stream>>>(grid, packed);
        gather_kernel<<<(n + block - 1) / block, block, 0, stream>>>(
            packed, vidx, ipos, mask, out, n);
    } else {
        sdf_grid_kernel<<<(n + block - 1) / block, block, 0, stream>>>(
            grid, vidx, ipos, vmin, mask, out, n);
    }
}